// Round 9
// baseline (358.490 us; speedup 1.0000x reference)
//
#include <hip/hip_runtime.h>

#define D 128
#define FILLV 0.5f
#define NXCD 8
#define EPT 8    // edges per thread in cnt

// Packed u32 bucket counter: count in bits[22:31], degree w*2^16 in bits[0:21].
// r8 scheme: 8 per-XCD replica tables + WORKGROUP-scope atomics -> RMW executes
// in the local XCD's L2 (no sc1 fabric bypass), instead of the ~22G op/s
// memory-side coherence point (r4/r6/r7 evidence). Replica index = physical
// XCC_ID (hardware fact, blocks never migrate) -> each replica touched by
// exactly one L2; kernel-end release flush publishes it.
#define CNT_SHIFT 22
#define DEG_MASK  0x3FFFFFu

typedef unsigned short u16;
typedef unsigned long long u64;
typedef unsigned uv4 __attribute__((ext_vector_type(4)));   // 16B nontemporal
typedef u64 u64v2 __attribute__((ext_vector_type(2)));      // 16B nontemporal
typedef u16 sv8 __attribute__((ext_vector_type(8)));        // 16B bf16x8 row slice

__device__ __forceinline__ u16 f2bf(float f) {          // RNE fp32 -> bf16
    unsigned u = __float_as_uint(f);
    u += 0x7FFF + ((u >> 16) & 1);
    return (u16)(u >> 16);
}
__device__ __forceinline__ float bf2f(u16 h) {
    return __uint_as_float(((unsigned)h) << 16);
}
__device__ __forceinline__ unsigned xcc_id() {          // physical XCD id 0..7
    unsigned x;
    asm volatile("s_getreg_b32 %0, hwreg(HW_REG_XCC_ID)" : "=s"(x));
    return x & 7;
}

// ---------------------------------------------------------------------------
// FUSED pass 1: edge blocks issue 2*EPT workgroup-scope packed u32 atomics
// into their own XCD's replica table; returns give per-replica ranks, stored
// as (xcc<<10)|rank per u16. Conversion blocks stream fp32->bf16 staging.
__global__ void cnt_tobf_kernel(const int* __restrict__ row, const int* __restrict__ col,
                                const float* __restrict__ w,
                                unsigned* __restrict__ rep, unsigned* __restrict__ ranks,
                                const float* __restrict__ x_s, const float* __restrict__ x_t,
                                u16* __restrict__ xb_s, u16* __restrict__ xb_t,
                                int E, int N, int nEB, long long nd) {
    if ((int)blockIdx.x < nEB) {
        long long g  = (long long)blockIdx.x * 256 + threadIdx.x;
        long long e0 = g * EPT;
        if (e0 >= E) return;
        unsigned x = xcc_id();
        size_t base = (size_t)x * (2u * (unsigned)N);
        unsigned xtag = x << 10;
        if (e0 + EPT <= E && (E & 3) == 0) {
            int rr[EPT]; int cc[EPT]; unsigned fx[EPT];
            #pragma unroll
            for (int h = 0; h < EPT / 4; ++h) {
                int q = (int)(e0 >> 2) + h;
                int4   r4 = *(const int4*)(row + 4 * (size_t)q);
                int4   c4 = *(const int4*)(col + 4 * (size_t)q);
                float4 w4 = *(const float4*)(w + 4 * (size_t)q);
                rr[4*h] = r4.x; rr[4*h+1] = r4.y; rr[4*h+2] = r4.z; rr[4*h+3] = r4.w;
                cc[4*h] = c4.x; cc[4*h+1] = c4.y; cc[4*h+2] = c4.z; cc[4*h+3] = c4.w;
                fx[4*h]   = (unsigned)(w4.x * 65536.0f);
                fx[4*h+1] = (unsigned)(w4.y * 65536.0f);
                fx[4*h+2] = (unsigned)(w4.z * 65536.0f);
                fx[4*h+3] = (unsigned)(w4.w * 65536.0f);
            }
            unsigned oc[EPT], orr[EPT];
            #pragma unroll
            for (int k = 0; k < EPT; ++k) {          // 16 L2-local RMWs in flight
                unsigned add = (1u << CNT_SHIFT) | fx[k];
                oc[k]  = __hip_atomic_fetch_add(&rep[base + (unsigned)cc[k]], add,
                                                __ATOMIC_RELAXED, __HIP_MEMORY_SCOPE_WORKGROUP);
                orr[k] = __hip_atomic_fetch_add(&rep[base + (unsigned)N + (unsigned)rr[k]], add,
                                                __ATOMIC_RELAXED, __HIP_MEMORY_SCOPE_WORKGROUP);
            }
            unsigned pk[EPT];
            #pragma unroll
            for (int k = 0; k < EPT; ++k)
                pk[k] = ((xtag | (orr[k] >> CNT_SHIFT)) << 16) | (xtag | (oc[k] >> CNT_SHIFT));
            uv4 pa = {pk[0], pk[1], pk[2], pk[3]};
            uv4 pb = {pk[4], pk[5], pk[6], pk[7]};
            __builtin_nontemporal_store(pa, (uv4*)(ranks + e0));
            __builtin_nontemporal_store(pb, (uv4*)(ranks + e0 + 4));
        } else {
            for (long long e = e0; e < E && e < e0 + EPT; ++e) {
                int r = row[e], c = col[e];
                unsigned add = (1u << CNT_SHIFT) | (unsigned)(w[e] * 65536.0f);
                unsigned oc  = __hip_atomic_fetch_add(&rep[base + (unsigned)c], add,
                                                      __ATOMIC_RELAXED, __HIP_MEMORY_SCOPE_WORKGROUP);
                unsigned orr = __hip_atomic_fetch_add(&rep[base + (unsigned)N + (unsigned)r], add,
                                                      __ATOMIC_RELAXED, __HIP_MEMORY_SCOPE_WORKGROUP);
                ranks[e] = ((xtag | (orr >> CNT_SHIFT)) << 16) | (xtag | (oc >> CNT_SHIFT));
            }
        }
    } else {
        long long t = (long long)(blockIdx.x - nEB) * 256 + threadIdx.x;
        long long q = nd / 4;
        const float* x; u16* xb; long long i;
        if (t < q) { x = x_s; xb = xb_s; i = t * 4; }
        else if (t < 2 * q) { x = x_t; xb = xb_t; i = (t - q) * 4; }
        else return;
        float4 v = *(const float4*)(x + i);
        ushort4 o;
        o.x = f2bf(v.x); o.y = f2bf(v.y); o.z = f2bf(v.z); o.w = f2bf(v.w);
        *(ushort4*)(xb + i) = o;
    }
}

// -------------------- merge replicas + invert + scan phase A ----------------
// Per bucket: load 8 replica values (coalesced per replica), total count ->
// cnttot + tsum; total degree -> dinv; in-place exclusive count-prefix over
// replicas (rep[x][i] <- sum_{y<x} cnt_y[i]).
__global__ void mergeAI_kernel(unsigned* __restrict__ rep, float* __restrict__ dinv,
                               unsigned* __restrict__ cnttot, int* __restrict__ tsum,
                               int total) {
    __shared__ int sh[256];
    int gid = blockIdx.x * 256 + threadIdx.x;
    int tot = 0;
    if (gid < total) {
        unsigned v[NXCD];
        #pragma unroll
        for (int x = 0; x < NXCD; ++x) v[x] = rep[(size_t)x * total + gid];
        unsigned run = 0, degsum = 0;
        #pragma unroll
        for (int x = 0; x < NXCD; ++x) {
            degsum += v[x] & DEG_MASK;
            rep[(size_t)x * total + gid] = run;
            run += v[x] >> CNT_SHIFT;
        }
        tot = (int)run;
        float deg = (float)degsum * (1.0f / 65536.0f);
        dinv[gid] = 1.0f / (deg + FILLV);
        cnttot[gid] = run;
    }
    sh[threadIdx.x] = tot;
    __syncthreads();
    for (int off = 128; off > 0; off >>= 1) {
        if (threadIdx.x < off) sh[threadIdx.x] += sh[threadIdx.x + off];
        __syncthreads();
    }
    if (threadIdx.x == 0) tsum[blockIdx.x] = sh[0];
}

// scanC with scanB folded in; also folds start[i] into every replica prefix
// so slot needs ONE gather per direction: slot = rep[x][bucket] + rank.
__global__ void scanC_kernel(const unsigned* __restrict__ cnttot, const int* __restrict__ tsum,
                             unsigned* __restrict__ rep,
                             int* __restrict__ start, int total, int grand_total) {
    __shared__ int sh[256];
    int acc = 0;
    for (int j = threadIdx.x; j < (int)blockIdx.x; j += 256) acc += tsum[j];
    sh[threadIdx.x] = acc;
    __syncthreads();
    for (int off = 128; off > 0; off >>= 1) {
        if (threadIdx.x < off) sh[threadIdx.x] += sh[threadIdx.x + off];
        __syncthreads();
    }
    int bpref = sh[0];
    __syncthreads();
    int gid = blockIdx.x * 256 + threadIdx.x;
    int v = (gid < total) ? (int)cnttot[gid] : 0;
    sh[threadIdx.x] = v;
    __syncthreads();
    for (int off = 1; off < 256; off <<= 1) {
        int u = 0;
        if (threadIdx.x >= off) u = sh[threadIdx.x - off];
        __syncthreads();
        sh[threadIdx.x] += u;
        __syncthreads();
    }
    int run = bpref + sh[threadIdx.x] - v;   // exclusive
    if (gid < total) {
        start[gid] = run;
        #pragma unroll
        for (int x = 0; x < NXCD; ++x) rep[(size_t)x * total + gid] += (unsigned)run;
    }
    if (gid == 0) start[total] = grand_total;
}

// Pass 2a: gathers once, emits coalesced record streams.
// slot = rep[xcc][bucket] + per-replica rank  (rep already includes start).
__global__ void slot_kernel(const unsigned* __restrict__ rep,
                            const int* __restrict__ row, const int* __restrict__ col,
                            const float* __restrict__ w, const unsigned* __restrict__ ranks,
                            const float* __restrict__ dinv,
                            u64* __restrict__ ssst, u64* __restrict__ es, u64* __restrict__ et,
                            int E, int N) {
    const int total = 2 * N;
    long long g  = (long long)blockIdx.x * blockDim.x + threadIdx.x;
    long long e0 = g * 4;
    if (e0 >= E) return;
    if (e0 + 4 <= E && (E & 3) == 0) {
        int q = (int)(e0 >> 2);
        int4   r4 = *(const int4*)(row + 4 * (size_t)q);
        int4   c4 = *(const int4*)(col + 4 * (size_t)q);
        float4 w4 = *(const float4*)(w + 4 * (size_t)q);
        uv4    p4 = __builtin_nontemporal_load((const uv4*)(ranks + e0));
        int rr[4] = {r4.x, r4.y, r4.z, r4.w};
        int cc[4] = {c4.x, c4.y, c4.z, c4.w};
        float ww[4] = {w4.x, w4.y, w4.z, w4.w};
        unsigned pk[4] = {p4.x, p4.y, p4.z, p4.w};
        #pragma unroll
        for (int k = 0; k < 4; ++k) {
            unsigned pks = pk[k] & 0xffffu, pkt = pk[k] >> 16;
            int ss = (int)(rep[(size_t)(pks >> 10) * total + cc[k]] + (pks & 0x3ffu));
            int st = (int)(rep[(size_t)(pkt >> 10) * total + (size_t)N + rr[k]] + (pkt & 0x3ffu));
            float wns = ww[k] * dinv[N + rr[k]];
            float wnt = ww[k] * dinv[cc[k]];
            u64 sv = ((u64)(unsigned)st << 32) | (unsigned)ss;
            u64 ev = ((u64)__float_as_uint(wns) << 32) | (unsigned)rr[k];
            u64 tv = ((u64)__float_as_uint(wnt) << 32) | (unsigned)cc[k];
            __builtin_nontemporal_store(sv, ssst + e0 + k);
            __builtin_nontemporal_store(ev, es + e0 + k);
            __builtin_nontemporal_store(tv, et + e0 + k);
        }
    } else {
        for (long long e = e0; e < E && e < e0 + 4; ++e) {
            int r = row[e], c = col[e];
            float we = w[e];
            unsigned pk = ranks[e];
            unsigned pks = pk & 0xffffu, pkt = pk >> 16;
            int ss = (int)(rep[(size_t)(pks >> 10) * total + c] + (pks & 0x3ffu));
            int st = (int)(rep[(size_t)(pkt >> 10) * total + (size_t)N + r] + (pkt & 0x3ffu));
            float wns = we * dinv[N + r];
            float wnt = we * dinv[c];
            __builtin_nontemporal_store(((u64)(unsigned)st << 32) | (unsigned)ss, ssst + e);
            __builtin_nontemporal_store(((u64)__float_as_uint(wns) << 32) | (unsigned)r, es + e);
            __builtin_nontemporal_store(((u64)__float_as_uint(wnt) << 32) | (unsigned)c, et + e);
        }
    }
}

// Pass 2b: XCD-range filter scatter (unchanged from r8).
__global__ void fillX_kernel(const u64* __restrict__ ssst,
                             const u64* __restrict__ es, const u64* __restrict__ et,
                             u64* __restrict__ edges, int E, int SL) {
    long long t = (long long)(blockIdx.x >> 3) * 256 + threadIdx.x;
    long long e0 = t * 2;
    int rid = blockIdx.x & 7;
    if (e0 >= E) return;
    int lo = rid * SL, hi = lo + SL;
    if (e0 + 2 <= E) {
        u64v2 sv = __builtin_nontemporal_load((const u64v2*)(ssst + e0));
        #pragma unroll
        for (int k = 0; k < 2; ++k) {
            int ss = (int)(unsigned)(sv[k] & 0xffffffffu);
            int st = (int)(unsigned)(sv[k] >> 32);
            if ((ss >= lo) & (ss < hi)) {
                u64 ev = __builtin_nontemporal_load(es + e0 + k);
                edges[ss] = ev;
            }
            if ((st >= lo) & (st < hi)) {
                u64 tv = __builtin_nontemporal_load(et + e0 + k);
                edges[st] = tv;
            }
        }
    } else {
        u64 sv = __builtin_nontemporal_load(ssst + e0);
        int ss = (int)(unsigned)(sv & 0xffffffffu);
        int st = (int)(unsigned)(sv >> 32);
        if ((ss >= lo) & (ss < hi)) edges[ss] = __builtin_nontemporal_load(es + e0);
        if ((st >= lo) & (st < hi)) edges[st] = __builtin_nontemporal_load(et + e0);
    }
}

// ---------------------------------------------------------------------------
// Pull kernels (unchanged from r8): wave per bucket; quarter-wave per edge
// (16 lanes x ushort8 = 256B row); 16 edges/iter main loop.
#define PULL_ACC4() \
    a0 += w0v*bf2f(v0[0]) + w1v*bf2f(v1[0]) + w2v*bf2f(v2[0]) + w3v*bf2f(v3[0]); \
    a1 += w0v*bf2f(v0[1]) + w1v*bf2f(v1[1]) + w2v*bf2f(v2[1]) + w3v*bf2f(v3[1]); \
    a2 += w0v*bf2f(v0[2]) + w1v*bf2f(v1[2]) + w2v*bf2f(v2[2]) + w3v*bf2f(v3[2]); \
    a3 += w0v*bf2f(v0[3]) + w1v*bf2f(v1[3]) + w2v*bf2f(v2[3]) + w3v*bf2f(v3[3]); \
    a4 += w0v*bf2f(v0[4]) + w1v*bf2f(v1[4]) + w2v*bf2f(v2[4]) + w3v*bf2f(v3[4]); \
    a5 += w0v*bf2f(v0[5]) + w1v*bf2f(v1[5]) + w2v*bf2f(v2[5]) + w3v*bf2f(v3[5]); \
    a6 += w0v*bf2f(v0[6]) + w1v*bf2f(v1[6]) + w2v*bf2f(v2[6]) + w3v*bf2f(v3[6]); \
    a7 += w0v*bf2f(v0[7]) + w1v*bf2f(v1[7]) + w2v*bf2f(v2[7]) + w3v*bf2f(v3[7]);

#define PULL_ACC2() \
    a0 += w0v*bf2f(v0[0]) + w1v*bf2f(v1[0]); a1 += w0v*bf2f(v0[1]) + w1v*bf2f(v1[1]); \
    a2 += w0v*bf2f(v0[2]) + w1v*bf2f(v1[2]); a3 += w0v*bf2f(v0[3]) + w1v*bf2f(v1[3]); \
    a4 += w0v*bf2f(v0[4]) + w1v*bf2f(v1[4]); a5 += w0v*bf2f(v0[5]) + w1v*bf2f(v1[5]); \
    a6 += w0v*bf2f(v0[6]) + w1v*bf2f(v1[6]); a7 += w0v*bf2f(v0[7]) + w1v*bf2f(v1[7]);

#define PULL_ACC1() \
    a0 += w0v*bf2f(v0[0]); a1 += w0v*bf2f(v0[1]); a2 += w0v*bf2f(v0[2]); \
    a3 += w0v*bf2f(v0[3]); a4 += w0v*bf2f(v0[4]); a5 += w0v*bf2f(v0[5]); \
    a6 += w0v*bf2f(v0[6]); a7 += w0v*bf2f(v0[7]);

#define PULL_BODY(SRC) \
    int s0 = start[wid], s1 = start[wid + 1]; \
    float a0=0.f,a1=0.f,a2=0.f,a3=0.f,a4=0.f,a5=0.f,a6=0.f,a7=0.f; \
    int k = s0; \
    for (; k + 16 <= s1; k += 16) { \
        int b = k + 4 * q; \
        int2 p0 = edges[b], p1 = edges[b+1], p2 = edges[b+2], p3 = edges[b+3]; \
        sv8 v0 = *(const sv8*)(SRC + (size_t)p0.x * D + ql * 8); \
        sv8 v1 = *(const sv8*)(SRC + (size_t)p1.x * D + ql * 8); \
        sv8 v2 = *(const sv8*)(SRC + (size_t)p2.x * D + ql * 8); \
        sv8 v3 = *(const sv8*)(SRC + (size_t)p3.x * D + ql * 8); \
        float w0v = __int_as_float(p0.y), w1v = __int_as_float(p1.y); \
        float w2v = __int_as_float(p2.y), w3v = __int_as_float(p3.y); \
        PULL_ACC4() \
    } \
    if (k + 8 <= s1) { \
        int b = k + 2 * q; \
        int2 p0 = edges[b], p1 = edges[b+1]; \
        sv8 v0 = *(const sv8*)(SRC + (size_t)p0.x * D + ql * 8); \
        sv8 v1 = *(const sv8*)(SRC + (size_t)p1.x * D + ql * 8); \
        float w0v = __int_as_float(p0.y), w1v = __int_as_float(p1.y); \
        PULL_ACC2() \
        k += 8; \
    } \
    if (k + 4 <= s1) { \
        int b = k + q; \
        int2 p0 = edges[b]; \
        sv8 v0 = *(const sv8*)(SRC + (size_t)p0.x * D + ql * 8); \
        float w0v = __int_as_float(p0.y); \
        PULL_ACC1() \
        k += 4; \
    } \
    for (; k < s1; ++k) { \
        if (q == 0) { \
            int2 p0 = edges[k]; \
            sv8 v0 = *(const sv8*)(SRC + (size_t)p0.x * D + ql * 8); \
            float w0v = __int_as_float(p0.y); \
            PULL_ACC1() \
        } \
    } \
    a0 += __shfl_xor(a0,16); a0 += __shfl_xor(a0,32); \
    a1 += __shfl_xor(a1,16); a1 += __shfl_xor(a1,32); \
    a2 += __shfl_xor(a2,16); a2 += __shfl_xor(a2,32); \
    a3 += __shfl_xor(a3,16); a3 += __shfl_xor(a3,32); \
    a4 += __shfl_xor(a4,16); a4 += __shfl_xor(a4,32); \
    a5 += __shfl_xor(a5,16); a5 += __shfl_xor(a5,32); \
    a6 += __shfl_xor(a6,16); a6 += __shfl_xor(a6,32); \
    a7 += __shfl_xor(a7,16); a7 += __shfl_xor(a7,32);

__global__ void pull1_kernel(const int* __restrict__ start, const int2* __restrict__ edges,
                             const float* __restrict__ dinv,
                             const u16* __restrict__ xb_s, const u16* __restrict__ xb_t,
                             const float* __restrict__ x_s, const float* __restrict__ x_t,
                             u16* __restrict__ ab_s, u16* __restrict__ ab_t, int N) {
    int wid0 = (int)(((long long)blockIdx.x * blockDim.x + threadIdx.x) >> 6);
    int wid = __builtin_amdgcn_readfirstlane(wid0);
    int lane = threadIdx.x & 63;
    int q = lane >> 4, ql = lane & 15;
    if (wid >= 2 * N) return;
    const u16* xb; const float* x; u16* ab; int i, o;
    if (wid < N) { i = wid;     o = N; xb = xb_s; x = x_s; ab = ab_s; }
    else         { i = wid - N; o = 0; xb = xb_t; x = x_t; ab = ab_t; }
    PULL_BODY(xb)
    if (q == 0) {
        float sw = FILLV * dinv[o + i];
        const float* xr = x + (size_t)i * D + ql * 8;
        float4 xv0 = *(const float4*)xr;
        float4 xv1 = *(const float4*)(xr + 4);
        a0 += sw * xv0.x; a1 += sw * xv0.y; a2 += sw * xv0.z; a3 += sw * xv0.w;
        a4 += sw * xv1.x; a5 += sw * xv1.y; a6 += sw * xv1.z; a7 += sw * xv1.w;
        sv8 ov;
        ov[0]=f2bf(a0); ov[1]=f2bf(a1); ov[2]=f2bf(a2); ov[3]=f2bf(a3);
        ov[4]=f2bf(a4); ov[5]=f2bf(a5); ov[6]=f2bf(a6); ov[7]=f2bf(a7);
        *(sv8*)(ab + (size_t)i * D + ql * 8) = ov;
    }
}

// Hop-2 pull + fused epilogue: out_half = w0*x + w1*a + w2*(conv(a)).
__global__ void pull2_kernel(const int* __restrict__ start, const int2* __restrict__ edges,
                             const float* __restrict__ dinv,
                             const u16* __restrict__ ab_s, const u16* __restrict__ ab_t,
                             const float* __restrict__ x_s, const float* __restrict__ x_t,
                             float* __restrict__ out,
                             const float* __restrict__ w_s, const float* __restrict__ w_t, int N) {
    int wid0 = (int)(((long long)blockIdx.x * blockDim.x + threadIdx.x) >> 6);
    int wid = __builtin_amdgcn_readfirstlane(wid0);
    int lane = threadIdx.x & 63;
    int q = lane >> 4, ql = lane & 15;
    if (wid >= 2 * N) return;
    const u16* ab; const float* x; const float* wv3; int i, o, hoff;
    if (wid < N) { i = wid;     o = N; ab = ab_s; x = x_s; wv3 = w_s; hoff = 0; }
    else         { i = wid - N; o = 0; ab = ab_t; x = x_t; wv3 = w_t; hoff = D; }
    PULL_BODY(ab)
    if (q == 0) {
        float sw = FILLV * dinv[o + i];
        sv8 av = *(const sv8*)(ab + (size_t)i * D + ql * 8);
        float b0=bf2f(av[0]), b1=bf2f(av[1]), b2=bf2f(av[2]), b3=bf2f(av[3]);
        float b4=bf2f(av[4]), b5=bf2f(av[5]), b6=bf2f(av[6]), b7=bf2f(av[7]);
        a0 += sw*b0; a1 += sw*b1; a2 += sw*b2; a3 += sw*b3;
        a4 += sw*b4; a5 += sw*b5; a6 += sw*b6; a7 += sw*b7;
        float w0 = wv3[0], w1 = wv3[1], w2 = wv3[2];
        const float* xr = x + (size_t)i * D + ql * 8;
        float4 xv0 = *(const float4*)xr;
        float4 xv1 = *(const float4*)(xr + 4);
        float4 o0, o1;
        o0.x = w0*xv0.x + w1*b0 + w2*a0;
        o0.y = w0*xv0.y + w1*b1 + w2*a1;
        o0.z = w0*xv0.z + w1*b2 + w2*a2;
        o0.w = w0*xv0.w + w1*b3 + w2*a3;
        o1.x = w0*xv1.x + w1*b4 + w2*a4;
        o1.y = w0*xv1.y + w1*b5 + w2*a5;
        o1.z = w0*xv1.z + w1*b6 + w2*a6;
        o1.w = w0*xv1.w + w1*b7 + w2*a7;
        float* orp = out + (size_t)i * 2 * D + hoff + ql * 8;
        *(float4*)orp = o0;
        *(float4*)(orp + 4) = o1;
    }
}

// ---------------------------------------------------------------------------
extern "C" void kernel_launch(void* const* d_in, const int* in_sizes, int n_in,
                              void* d_out, int out_size, void* d_ws, size_t ws_size,
                              hipStream_t stream) {
    const float* x_s = (const float*)d_in[0];
    const float* x_t = (const float*)d_in[1];
    const int*   ei  = (const int*)d_in[2];
    const float* ew  = (const float*)d_in[3];
    const float* w_s = (const float*)d_in[4];
    const float* w_t = (const float*)d_in[5];
    const int N = in_sizes[0] / D;
    const int E = in_sizes[3];
    const int* row = ei;
    const int* col = ei + E;

    const int total = 2 * N;
    const int nTiles = (total + 255) / 256;

    // Workspace (d_ws): [dinv 2N][start 2N+2][tsum 512][align]
    // [edges 2E int2 (64B-aligned)] [xb_s ND u16][xb_t ND u16][ab_s][ab_t]
    // rep (8*2N u32 = 3.2MB) + cnttot (2N u32) alias ab_s: dead before pull1.
    float* f      = (float*)d_ws;
    float* dinv   = f;                              // 2N
    int*   start  = (int*)(f + (size_t)total);      // 2N+2
    int*   tsum   = start + (total + 2);            // 512
    char*  pc     = (char*)(tsum + 512);
    pc = (char*)(((size_t)pc + 255) & ~(size_t)255);
    u64*   edges  = (u64*)pc;                       // 2E int2, 64B-aligned
    u16*   xb_s   = (u16*)(edges + 2 * (size_t)E);
    u16*   xb_t   = xb_s + (size_t)N * D;
    u16*   ab_s   = xb_t + (size_t)N * D;
    u16*   ab_t   = ab_s + (size_t)N * D;
    unsigned* rep    = (unsigned*)ab_s;             // 8*2N, dead before pull1
    unsigned* cnttot = rep + (size_t)NXCD * total;  // 2N

    // d_out scratch (dead until pull2 writes): ranks[E] u32, then streams
    // ssst/es/et (u64[E] each), 16B-aligned. Total ~28E bytes.
    unsigned* ranks = (unsigned*)d_out;
    char* po = (char*)d_out + (((size_t)E * 4 + 15) & ~(size_t)15);
    u64* ssst = (u64*)po;
    u64* es   = ssst + (size_t)E;
    u64* et   = es + (size_t)E;
    float* out = (float*)d_out;

    hipMemsetAsync(rep, 0, (size_t)NXCD * total * sizeof(unsigned), stream);

    long long nd = (long long)N * D;
    int blkC = (int)((nd / 2 + 255) / 256);
    int nEB  = (E + EPT * 256 - 1) / (EPT * 256);
    cnt_tobf_kernel<<<nEB + blkC, 256, 0, stream>>>(row, col, ew, rep, ranks,
                                                    x_s, x_t, xb_s, xb_t,
                                                    E, N, nEB, nd);
    mergeAI_kernel<<<nTiles, 256, 0, stream>>>(rep, dinv, cnttot, tsum, total);
    scanC_kernel<<<nTiles, 256, 0, stream>>>(cnttot, tsum, rep, start, total, 2 * E);

    int blkS = (E / 4 + 256) / 256 + 1;
    slot_kernel<<<blkS, 256, 0, stream>>>(rep, row, col, ew, ranks, dinv,
                                          ssst, es, et, E, N);

    // slot-range size per XCD, multiple of 8 slots (64B lines of int2)
    int SL = ((2 * E + NXCD - 1) / NXCD + 7) & ~7;
    int blkF = (E + 511) / 512;
    fillX_kernel<<<NXCD * blkF, 256, 0, stream>>>(ssst, es, et, edges, E, SL);

    long long pull_threads = (long long)total * 64;
    int blkP = (int)((pull_threads + 255) / 256);
    pull1_kernel<<<blkP, 256, 0, stream>>>(start, (const int2*)edges, dinv, xb_s, xb_t,
                                           x_s, x_t, ab_s, ab_t, N);
    pull2_kernel<<<blkP, 256, 0, stream>>>(start, (const int2*)edges, dinv, ab_s, ab_t,
                                           x_s, x_t, out, w_s, w_t, N);
}

// Round 10
// 337.424 us; speedup vs baseline: 1.0624x; 1.0624x over previous
//
#include <hip/hip_runtime.h>

#define D 128
#define FILLV 0.5f
#define NXCD 8
#define EPT 8    // edges per thread in cnt

// Packed u32 bucket counter: count in bits[22:31], degree w*2^16 in bits[0:21].
// cnt floor established (r4/r6/r7/r9): device-scope RMW point retires ~22G op/s,
// per-op bound (layout/MLP/width/scope-insensitive). 1.6M returned RMWs irreducible.
#define CNT_SHIFT 22
#define DEG_MASK  0x3FFFFFu

typedef unsigned short u16;
typedef unsigned long long u64;
typedef unsigned uv4 __attribute__((ext_vector_type(4)));   // 16B nontemporal
typedef u64 u64v2 __attribute__((ext_vector_type(2)));      // 16B nontemporal

__device__ __forceinline__ u16 f2bf(float f) {          // RNE fp32 -> bf16
    unsigned u = __float_as_uint(f);
    u += 0x7FFF + ((u >> 16) & 1);
    return (u16)(u >> 16);
}
__device__ __forceinline__ float bf2f(u16 h) {
    return __uint_as_float(((unsigned)h) << 16);
}

// ---------------------------------------------------------------------------
// FUSED pass 1 (r7, at its atomic floor): edge blocks issue 2*EPT independent
// packed u32 atomics; returns give within-bucket ranks (u16x2). Conversion
// blocks stream fp32->bf16 staging under the atomic latency.
__global__ void cnt_tobf_kernel(const int* __restrict__ row, const int* __restrict__ col,
                                const float* __restrict__ w,
                                unsigned* __restrict__ cnt32, unsigned* __restrict__ ranks,
                                const float* __restrict__ x_s, const float* __restrict__ x_t,
                                u16* __restrict__ xb_s, u16* __restrict__ xb_t,
                                int E, int N, int nEB, long long nd) {
    if ((int)blockIdx.x < nEB) {
        long long g  = (long long)blockIdx.x * 256 + threadIdx.x;
        long long e0 = g * EPT;
        if (e0 >= E) return;
        if (e0 + EPT <= E && (E & 3) == 0) {
            int rr[EPT]; int cc[EPT]; unsigned fx[EPT];
            #pragma unroll
            for (int h = 0; h < EPT / 4; ++h) {
                int q = (int)(e0 >> 2) + h;
                int4   r4 = *(const int4*)(row + 4 * (size_t)q);
                int4   c4 = *(const int4*)(col + 4 * (size_t)q);
                float4 w4 = *(const float4*)(w + 4 * (size_t)q);
                rr[4*h] = r4.x; rr[4*h+1] = r4.y; rr[4*h+2] = r4.z; rr[4*h+3] = r4.w;
                cc[4*h] = c4.x; cc[4*h+1] = c4.y; cc[4*h+2] = c4.z; cc[4*h+3] = c4.w;
                fx[4*h]   = (unsigned)(w4.x * 65536.0f);
                fx[4*h+1] = (unsigned)(w4.y * 65536.0f);
                fx[4*h+2] = (unsigned)(w4.z * 65536.0f);
                fx[4*h+3] = (unsigned)(w4.w * 65536.0f);
            }
            unsigned oc[EPT], orr[EPT];
            #pragma unroll
            for (int k = 0; k < EPT; ++k) {
                unsigned add = (1u << CNT_SHIFT) | fx[k];
                oc[k]  = atomicAdd(&cnt32[(size_t)cc[k]], add);
                orr[k] = atomicAdd(&cnt32[(size_t)N + rr[k]], add);
            }
            unsigned pk[EPT];
            #pragma unroll
            for (int k = 0; k < EPT; ++k)
                pk[k] = ((orr[k] >> CNT_SHIFT) << 16) | (oc[k] >> CNT_SHIFT);
            uv4 pa = {pk[0], pk[1], pk[2], pk[3]};
            uv4 pb = {pk[4], pk[5], pk[6], pk[7]};
            __builtin_nontemporal_store(pa, (uv4*)(ranks + e0));
            __builtin_nontemporal_store(pb, (uv4*)(ranks + e0 + 4));
        } else {
            for (long long e = e0; e < E && e < e0 + EPT; ++e) {
                int r = row[e], c = col[e];
                unsigned add = (1u << CNT_SHIFT) | (unsigned)(w[e] * 65536.0f);
                unsigned oc  = atomicAdd(&cnt32[(size_t)c], add);
                unsigned orr = atomicAdd(&cnt32[(size_t)N + r], add);
                ranks[e] = ((orr >> CNT_SHIFT) << 16) | (oc >> CNT_SHIFT);
            }
        }
    } else {
        long long t = (long long)(blockIdx.x - nEB) * 256 + threadIdx.x;
        long long q = nd / 4;
        const float* x; u16* xb; long long i;
        if (t < q) { x = x_s; xb = xb_s; i = t * 4; }
        else if (t < 2 * q) { x = x_t; xb = xb_t; i = (t - q) * 4; }
        else return;
        float4 v = *(const float4*)(x + i);
        ushort4 o;
        o.x = f2bf(v.x); o.y = f2bf(v.y); o.z = f2bf(v.z); o.w = f2bf(v.w);
        *(ushort4*)(xb + i) = o;
    }
}

// -------------------- fused invert + scan phase A ---------------------------
__global__ void scanAI_kernel(unsigned* __restrict__ cnt32, float* __restrict__ dinv,
                              int* __restrict__ tsum, int total) {
    __shared__ int sh[256];
    int gid = blockIdx.x * 256 + threadIdx.x;
    int cnt = 0;
    if (gid < total) {
        unsigned v = cnt32[gid];
        float deg = (float)(v & DEG_MASK) * (1.0f / 65536.0f);
        dinv[gid] = 1.0f / (deg + FILLV);
        cnt = (int)(v >> CNT_SHIFT);
        cnt32[gid] = (unsigned)cnt;
    }
    sh[threadIdx.x] = cnt;
    __syncthreads();
    for (int off = 128; off > 0; off >>= 1) {
        if (threadIdx.x < off) sh[threadIdx.x] += sh[threadIdx.x + off];
        __syncthreads();
    }
    if (threadIdx.x == 0) tsum[blockIdx.x] = sh[0];
}

// scanC with scanB folded in.
__global__ void scanC_kernel(const unsigned* __restrict__ cnt32, const int* __restrict__ tsum,
                             int* __restrict__ start, int total, int grand_total) {
    __shared__ int sh[256];
    int acc = 0;
    for (int j = threadIdx.x; j < (int)blockIdx.x; j += 256) acc += tsum[j];
    sh[threadIdx.x] = acc;
    __syncthreads();
    for (int off = 128; off > 0; off >>= 1) {
        if (threadIdx.x < off) sh[threadIdx.x] += sh[threadIdx.x + off];
        __syncthreads();
    }
    int bpref = sh[0];
    __syncthreads();
    int gid = blockIdx.x * 256 + threadIdx.x;
    int v = (gid < total) ? (int)cnt32[gid] : 0;
    sh[threadIdx.x] = v;
    __syncthreads();
    for (int off = 1; off < 256; off <<= 1) {
        int u = 0;
        if (threadIdx.x >= off) u = sh[threadIdx.x - off];
        __syncthreads();
        sh[threadIdx.x] += u;
        __syncthreads();
    }
    int run = bpref + sh[threadIdx.x] - v;   // exclusive
    if (gid < total) start[gid] = run;
    if (gid == 0) start[total] = grand_total;
}

// Pass 2a (slot2): compute records once AND bin them by slot-range. Slots are
// a permutation of [0,2E) -> bin b holds exactly the records with slot in
// [b*SL,(b+1)*SL): closed-form sizes, binbuf base = b*SL. Placement within a
// bin is arrival-order via {LDS histogram rank + 8 global cursor atomics/WG}
// (6K device RMWs total - negligible vs cnt's 1.6M). Replaces fillX's 8x
// redundant stream (51MB) + predicated overfetch (~34MB) with a dense binned
// write (19.2MB) that fill2 reads back exactly once.
__global__ void slot2_kernel(const int* __restrict__ start,
                             const int* __restrict__ row, const int* __restrict__ col,
                             const float* __restrict__ w, const unsigned* __restrict__ ranks,
                             const float* __restrict__ dinv,
                             unsigned* __restrict__ cursor,
                             unsigned* __restrict__ bslot, u64* __restrict__ bpay,
                             int E, int N, int SL) {
    __shared__ unsigned hist[NXCD];
    __shared__ unsigned wbase[NXCD];
    if (threadIdx.x < NXCD) hist[threadIdx.x] = 0;
    __syncthreads();
    long long g  = (long long)blockIdx.x * 256 + threadIdx.x;
    long long e0 = g * 4;
    unsigned rslot[8]; u64 rpay[8]; unsigned rbin[8], rrank[8];
    int nrec = 0;
    if (e0 < E) {
        if (e0 + 4 <= E && (E & 3) == 0) {
            int q = (int)(e0 >> 2);
            int4   r4 = *(const int4*)(row + 4 * (size_t)q);
            int4   c4 = *(const int4*)(col + 4 * (size_t)q);
            float4 w4 = *(const float4*)(w + 4 * (size_t)q);
            uv4    p4 = __builtin_nontemporal_load((const uv4*)(ranks + e0));
            int rr[4] = {r4.x, r4.y, r4.z, r4.w};
            int cc[4] = {c4.x, c4.y, c4.z, c4.w};
            float ww[4] = {w4.x, w4.y, w4.z, w4.w};
            unsigned pk[4] = {p4.x, p4.y, p4.z, p4.w};
            #pragma unroll
            for (int k = 0; k < 4; ++k) {
                int ss = start[cc[k]] + (int)(pk[k] & 0xffffu);
                int st = start[N + rr[k]] + (int)(pk[k] >> 16);
                float wns = ww[k] * dinv[N + rr[k]];
                float wnt = ww[k] * dinv[cc[k]];
                rslot[nrec] = (unsigned)ss;
                rpay[nrec]  = ((u64)__float_as_uint(wns) << 32) | (unsigned)rr[k];
                ++nrec;
                rslot[nrec] = (unsigned)st;
                rpay[nrec]  = ((u64)__float_as_uint(wnt) << 32) | (unsigned)cc[k];
                ++nrec;
            }
        } else {
            for (long long e = e0; e < E && e < e0 + 4; ++e) {
                int r = row[e], c = col[e];
                float we = w[e];
                unsigned pk = ranks[e];
                int ss = start[c] + (int)(pk & 0xffffu);
                int st = start[N + r] + (int)(pk >> 16);
                float wns = we * dinv[N + r];
                float wnt = we * dinv[c];
                rslot[nrec] = (unsigned)ss;
                rpay[nrec]  = ((u64)__float_as_uint(wns) << 32) | (unsigned)r;
                ++nrec;
                rslot[nrec] = (unsigned)st;
                rpay[nrec]  = ((u64)__float_as_uint(wnt) << 32) | (unsigned)c;
                ++nrec;
            }
        }
        for (int j = 0; j < nrec; ++j) {
            rbin[j]  = rslot[j] / (unsigned)SL;
            rrank[j] = atomicAdd(&hist[rbin[j]], 1u);
        }
    }
    __syncthreads();
    if (threadIdx.x < NXCD)
        wbase[threadIdx.x] = atomicAdd(&cursor[threadIdx.x], hist[threadIdx.x]);
    __syncthreads();
    for (int j = 0; j < nrec; ++j) {
        unsigned pos = rbin[j] * (unsigned)SL + wbase[rbin[j]] + rrank[j];
        bslot[pos] = rslot[j];
        bpay[pos]  = rpay[j];
    }
}

// Pass 2b (fill2): block rid=blockIdx&7 reads ONLY bin rid (sequential,
// exactly once) and scatter-writes into its own 1.6MB slot window -> the ~8
// payloads sharing a 64B line merge in ONE XCD's L2 (round-robin dispatch
// heuristic; correctness holds regardless of placement). Bin sizes are
// closed-form (slot permutation), no cursor read needed.
__global__ void fill2_kernel(const unsigned* __restrict__ bslot, const u64* __restrict__ bpay,
                             u64* __restrict__ edges, int E2, int SL) {
    int rid = blockIdx.x & 7;
    long long idx = ((long long)(blockIdx.x >> 3) * 256 + threadIdx.x) * 2;
    long long lo  = (long long)rid * SL;
    long long rem = (long long)E2 - lo;
    int cntb = rem < 0 ? 0 : (rem > SL ? SL : (int)rem);
    if (idx >= cntb) return;
    long long p = lo + idx;
    if (idx + 2 <= cntb) {
        u64   s2 = __builtin_nontemporal_load((const u64*)(bslot + p));
        u64v2 y2 = __builtin_nontemporal_load((const u64v2*)(bpay + p));
        unsigned s0 = (unsigned)(s2 & 0xffffffffu), s1 = (unsigned)(s2 >> 32);
        edges[s0] = y2[0];
        edges[s1] = y2[1];
    } else {
        edges[bslot[p]] = __builtin_nontemporal_load(bpay + p);
    }
}

// ---------------------------------------------------------------------------
// Pull kernels (r7 half-wave, best measured): wave per bucket; HALF-WAVE per
// edge (bf16 row = 256B = 32 lanes x ushort4). Main loop 8 edges/iter.
__global__ void pull1_kernel(const int* __restrict__ start, const int2* __restrict__ edges,
                             const float* __restrict__ dinv,
                             const u16* __restrict__ xb_s, const u16* __restrict__ xb_t,
                             const float* __restrict__ x_s, const float* __restrict__ x_t,
                             u16* __restrict__ ab_s, u16* __restrict__ ab_t, int N) {
    int wid0 = (int)(((long long)blockIdx.x * blockDim.x + threadIdx.x) >> 6);
    int wid = __builtin_amdgcn_readfirstlane(wid0);
    int lane = threadIdx.x & 63;
    int half = lane >> 5, hl = lane & 31;
    if (wid >= 2 * N) return;
    const u16* xb; const float* x; u16* ab; int i, o;
    if (wid < N) { i = wid;     o = N; xb = xb_s; x = x_s; ab = ab_s; }
    else         { i = wid - N; o = 0; xb = xb_t; x = x_t; ab = ab_t; }
    int s0 = start[wid], s1 = start[wid + 1];
    float a0 = 0.f, a1 = 0.f, a2 = 0.f, a3 = 0.f;
    int k = s0;
    for (; k + 8 <= s1; k += 8) {
        int b = k + 4 * half;
        int2 p0 = edges[b], p1 = edges[b + 1], p2 = edges[b + 2], p3 = edges[b + 3];
        ushort4 v0 = *(const ushort4*)(xb + (size_t)p0.x * D + hl * 4);
        ushort4 v1 = *(const ushort4*)(xb + (size_t)p1.x * D + hl * 4);
        ushort4 v2 = *(const ushort4*)(xb + (size_t)p2.x * D + hl * 4);
        ushort4 v3 = *(const ushort4*)(xb + (size_t)p3.x * D + hl * 4);
        float w0v = __int_as_float(p0.y), w1v = __int_as_float(p1.y);
        float w2v = __int_as_float(p2.y), w3v = __int_as_float(p3.y);
        a0 += w0v * bf2f(v0.x) + w1v * bf2f(v1.x) + w2v * bf2f(v2.x) + w3v * bf2f(v3.x);
        a1 += w0v * bf2f(v0.y) + w1v * bf2f(v1.y) + w2v * bf2f(v2.y) + w3v * bf2f(v3.y);
        a2 += w0v * bf2f(v0.z) + w1v * bf2f(v1.z) + w2v * bf2f(v2.z) + w3v * bf2f(v3.z);
        a3 += w0v * bf2f(v0.w) + w1v * bf2f(v1.w) + w2v * bf2f(v2.w) + w3v * bf2f(v3.w);
    }
    if (k + 4 <= s1) {
        int b = k + 2 * half;
        int2 p0 = edges[b], p1 = edges[b + 1];
        ushort4 v0 = *(const ushort4*)(xb + (size_t)p0.x * D + hl * 4);
        ushort4 v1 = *(const ushort4*)(xb + (size_t)p1.x * D + hl * 4);
        float w0v = __int_as_float(p0.y), w1v = __int_as_float(p1.y);
        a0 += w0v * bf2f(v0.x) + w1v * bf2f(v1.x);
        a1 += w0v * bf2f(v0.y) + w1v * bf2f(v1.y);
        a2 += w0v * bf2f(v0.z) + w1v * bf2f(v1.z);
        a3 += w0v * bf2f(v0.w) + w1v * bf2f(v1.w);
        k += 4;
    }
    for (; k < s1; ++k) {
        if (half == 0) {
            int2 p = edges[k];
            ushort4 v = *(const ushort4*)(xb + (size_t)p.x * D + hl * 4);
            float wv = __int_as_float(p.y);
            a0 += wv * bf2f(v.x); a1 += wv * bf2f(v.y);
            a2 += wv * bf2f(v.z); a3 += wv * bf2f(v.w);
        }
    }
    a0 += __shfl_xor(a0, 32); a1 += __shfl_xor(a1, 32);
    a2 += __shfl_xor(a2, 32); a3 += __shfl_xor(a3, 32);
    if (half == 0) {
        float sw = FILLV * dinv[o + i];
        float4 xv = *(const float4*)(x + (size_t)i * D + hl * 4);
        a0 += sw * xv.x; a1 += sw * xv.y; a2 += sw * xv.z; a3 += sw * xv.w;
        ushort4 ov;
        ov.x = f2bf(a0); ov.y = f2bf(a1); ov.z = f2bf(a2); ov.w = f2bf(a3);
        *(ushort4*)(ab + (size_t)i * D + hl * 4) = ov;
    }
}

// Hop-2 pull + fused epilogue: out_half = w0*x + w1*a + w2*(conv(a)).
__global__ void pull2_kernel(const int* __restrict__ start, const int2* __restrict__ edges,
                             const float* __restrict__ dinv,
                             const u16* __restrict__ ab_s, const u16* __restrict__ ab_t,
                             const float* __restrict__ x_s, const float* __restrict__ x_t,
                             float* __restrict__ out,
                             const float* __restrict__ w_s, const float* __restrict__ w_t, int N) {
    int wid0 = (int)(((long long)blockIdx.x * blockDim.x + threadIdx.x) >> 6);
    int wid = __builtin_amdgcn_readfirstlane(wid0);
    int lane = threadIdx.x & 63;
    int half = lane >> 5, hl = lane & 31;
    if (wid >= 2 * N) return;
    const u16* ab; const float* x; const float* wv3; int i, o, hoff;
    if (wid < N) { i = wid;     o = N; ab = ab_s; x = x_s; wv3 = w_s; hoff = 0; }
    else         { i = wid - N; o = 0; ab = ab_t; x = x_t; wv3 = w_t; hoff = D; }
    int s0 = start[wid], s1 = start[wid + 1];
    float a0 = 0.f, a1 = 0.f, a2 = 0.f, a3 = 0.f;
    int k = s0;
    for (; k + 8 <= s1; k += 8) {
        int b = k + 4 * half;
        int2 p0 = edges[b], p1 = edges[b + 1], p2 = edges[b + 2], p3 = edges[b + 3];
        ushort4 v0 = *(const ushort4*)(ab + (size_t)p0.x * D + hl * 4);
        ushort4 v1 = *(const ushort4*)(ab + (size_t)p1.x * D + hl * 4);
        ushort4 v2 = *(const ushort4*)(ab + (size_t)p2.x * D + hl * 4);
        ushort4 v3 = *(const ushort4*)(ab + (size_t)p3.x * D + hl * 4);
        float w0v = __int_as_float(p0.y), w1v = __int_as_float(p1.y);
        float w2v = __int_as_float(p2.y), w3v = __int_as_float(p3.y);
        a0 += w0v * bf2f(v0.x) + w1v * bf2f(v1.x) + w2v * bf2f(v2.x) + w3v * bf2f(v3.x);
        a1 += w0v * bf2f(v0.y) + w1v * bf2f(v1.y) + w2v * bf2f(v2.y) + w3v * bf2f(v3.y);
        a2 += w0v * bf2f(v0.z) + w1v * bf2f(v1.z) + w2v * bf2f(v2.z) + w3v * bf2f(v3.z);
        a3 += w0v * bf2f(v0.w) + w1v * bf2f(v1.w) + w2v * bf2f(v2.w) + w3v * bf2f(v3.w);
    }
    if (k + 4 <= s1) {
        int b = k + 2 * half;
        int2 p0 = edges[b], p1 = edges[b + 1];
        ushort4 v0 = *(const ushort4*)(ab + (size_t)p0.x * D + hl * 4);
        ushort4 v1 = *(const ushort4*)(ab + (size_t)p1.x * D + hl * 4);
        float w0v = __int_as_float(p0.y), w1v = __int_as_float(p1.y);
        a0 += w0v * bf2f(v0.x) + w1v * bf2f(v1.x);
        a1 += w0v * bf2f(v0.y) + w1v * bf2f(v1.y);
        a2 += w0v * bf2f(v0.z) + w1v * bf2f(v1.z);
        a3 += w0v * bf2f(v0.w) + w1v * bf2f(v1.w);
        k += 4;
    }
    for (; k < s1; ++k) {
        if (half == 0) {
            int2 p = edges[k];
            ushort4 v = *(const ushort4*)(ab + (size_t)p.x * D + hl * 4);
            float wv = __int_as_float(p.y);
            a0 += wv * bf2f(v.x); a1 += wv * bf2f(v.y);
            a2 += wv * bf2f(v.z); a3 += wv * bf2f(v.w);
        }
    }
    a0 += __shfl_xor(a0, 32); a1 += __shfl_xor(a1, 32);
    a2 += __shfl_xor(a2, 32); a3 += __shfl_xor(a3, 32);
    if (half == 0) {
        float sw = FILLV * dinv[o + i];
        ushort4 av = *(const ushort4*)(ab + (size_t)i * D + hl * 4);
        float b0 = bf2f(av.x), b1 = bf2f(av.y), b2 = bf2f(av.z), b3 = bf2f(av.w);
        a0 += sw * b0; a1 += sw * b1; a2 += sw * b2; a3 += sw * b3;
        float w0 = wv3[0], w1 = wv3[1], w2 = wv3[2];
        float4 xv = *(const float4*)(x + (size_t)i * D + hl * 4);
        float4 ov;
        ov.x = w0 * xv.x + w1 * b0 + w2 * a0;
        ov.y = w0 * xv.y + w1 * b1 + w2 * a1;
        ov.z = w0 * xv.z + w1 * b2 + w2 * a2;
        ov.w = w0 * xv.w + w1 * b3 + w2 * a3;
        *(float4*)(out + (size_t)i * 2 * D + hoff + hl * 4) = ov;
    }
}

// ---------------------------------------------------------------------------
extern "C" void kernel_launch(void* const* d_in, const int* in_sizes, int n_in,
                              void* d_out, int out_size, void* d_ws, size_t ws_size,
                              hipStream_t stream) {
    const float* x_s = (const float*)d_in[0];
    const float* x_t = (const float*)d_in[1];
    const int*   ei  = (const int*)d_in[2];
    const float* ew  = (const float*)d_in[3];
    const float* w_s = (const float*)d_in[4];
    const float* w_t = (const float*)d_in[5];
    const int N = in_sizes[0] / D;
    const int E = in_sizes[3];
    const int* row = ei;
    const int* col = ei + E;

    const int total = 2 * N;
    const int nTiles = (total + 255) / 256;
    const int SL = ((2 * E + NXCD - 1) / NXCD + 7) & ~7;   // bin/range size

    // Workspace (d_ws): [dinv 2N][start 2N+2][tsum 512][align]
    // [edges 2E int2 (64B-aligned)] [xb_s ND u16][xb_t ND u16][ab_s][ab_t]
    // cnt32 (2N u32) + cursor (8 u32) alias ab_s: dead before pull1.
    float* f      = (float*)d_ws;
    float* dinv   = f;                              // 2N
    int*   start  = (int*)(f + (size_t)total);      // 2N+2
    int*   tsum   = start + (total + 2);            // 512
    char*  pc     = (char*)(tsum + 512);
    pc = (char*)(((size_t)pc + 255) & ~(size_t)255);
    u64*   edges  = (u64*)pc;                       // 2E int2, 64B-aligned
    u16*   xb_s   = (u16*)(edges + 2 * (size_t)E);
    u16*   xb_t   = xb_s + (size_t)N * D;
    u16*   ab_s   = xb_t + (size_t)N * D;
    u16*   ab_t   = ab_s + (size_t)N * D;
    unsigned* cnt32  = (unsigned*)ab_s;             // 2N, dead before pull1
    unsigned* cursor = cnt32 + (size_t)total;       // 8 bin cursors

    // d_out scratch (dead until pull2 writes): ranks u32[E], then binned
    // records bslot u32[8SL] + bpay u64[8SL] (16B-aligned). ~22.4MB total.
    unsigned* ranks = (unsigned*)d_out;
    char* po = (char*)d_out + (((size_t)E * 4 + 15) & ~(size_t)15);
    unsigned* bslot = (unsigned*)po;                           // 8SL u32
    u64*      bpay  = (u64*)(bslot + (size_t)NXCD * SL);       // 8SL u64
    float* out = (float*)d_out;

    hipMemsetAsync(cnt32, 0, ((size_t)total + NXCD) * sizeof(unsigned), stream);

    long long nd = (long long)N * D;
    int blkC = (int)((nd / 2 + 255) / 256);
    int nEB  = (E + EPT * 256 - 1) / (EPT * 256);
    cnt_tobf_kernel<<<nEB + blkC, 256, 0, stream>>>(row, col, ew, cnt32, ranks,
                                                    x_s, x_t, xb_s, xb_t,
                                                    E, N, nEB, nd);
    scanAI_kernel<<<nTiles, 256, 0, stream>>>(cnt32, dinv, tsum, total);
    scanC_kernel<<<nTiles, 256, 0, stream>>>(cnt32, tsum, start, total, 2 * E);

    int blkS = (E + 1023) / 1024;                   // 4 edges/thread
    slot2_kernel<<<blkS, 256, 0, stream>>>(start, row, col, ew, ranks, dinv,
                                           cursor, bslot, bpay, E, N, SL);

    int blkF = 8 * ((SL + 511) / 512);              // 2 records/thread per bin
    fill2_kernel<<<blkF, 256, 0, stream>>>(bslot, bpay, edges, 2 * E, SL);

    long long pull_threads = (long long)total * 64;
    int blkP = (int)((pull_threads + 255) / 256);
    pull1_kernel<<<blkP, 256, 0, stream>>>(start, (const int2*)edges, dinv, xb_s, xb_t,
                                           x_s, x_t, ab_s, ab_t, N);
    pull2_kernel<<<blkP, 256, 0, stream>>>(start, (const int2*)edges, dinv, ab_s, ab_t,
                                           x_s, x_t, out, w_s, w_t, N);
}